// Round 7
// baseline (173.995 us; speedup 1.0000x reference)
//
#include <hip/hip_runtime.h>
#include <hip/hip_cooperative_groups.h>
#include <hip/hip_bf16.h>
#include <math.h>

namespace cg = cooperative_groups;

#define NUM_OBJECTS 80000
#define EPS_W 1e-5f
#define EPS_A 1e-7f

// packed per-object accumulator (u32): bits [31:8] = sum(loss) in 2^18 fixed
// point, bits [7:0] = count. loss in [0,2]; per-object count ~Poisson(5),
// max ~30 << 255; sum < 2^24 -> no overflow, count never carries into sum.
#define LOSS_SCALE_F 262144.0f   // 2^18
#define INV_LOSS_SCALE_F (1.0f / 262144.0f)

// ws layout: table 80000 u32 (=20000 uint4) | acc 2 f32 + 2 pad (1 uint4)
#define TABLE_VEC4 20000
#define ZERO_VEC16 20001

__device__ __forceinline__ void corner_minmax(float X, float Y, float Wc,
                                              float& minx, float& maxx,
                                              float& miny, float& maxy) {
    float wd = fmaxf(Wc, EPS_W);
    float r  = __builtin_amdgcn_rcpf(wd);   // v_rcp_f32, ~1 ulp
    float xi = X * r;
    float yi = Y * r;
    minx = fminf(minx, xi); maxx = fmaxf(maxx, xi);
    miny = fminf(miny, yi); maxy = fmaxf(maxy, yi);
}

__device__ __forceinline__ float box_loss(const float* __restrict__ p, int j,
                                          const float* __restrict__ l2i,
                                          const float* __restrict__ imgsh,
                                          const float* __restrict__ gt2d,
                                          int i) {
    float x = p[7*j+0], y = p[7*j+1], z = p[7*j+2];
    float hl = 0.5f * p[7*j+3], hw = 0.5f * p[7*j+4], hh = 0.5f * p[7*j+5];
    float yaw = p[7*j+6];
    float s, c;
    __sincosf(yaw, &s, &c);

    const float4* M = (const float4*)(l2i + 16 * (size_t)i);
    float4 M0 = M[0];
    float4 M1 = M[1];
    float4 M2 = M[2];

    // X(corner) = bx + sx*Ax + sy*Bx + sz*Cx (affine in the sign triple)
    float bx = M0.x * x + M0.y * y + M0.z * z + M0.w;
    float by = M1.x * x + M1.y * y + M1.z * z + M1.w;
    float bw = M2.x * x + M2.y * y + M2.z * z + M2.w;
    float Ax = (M0.x * c + M0.y * s) * hl;
    float Ay = (M1.x * c + M1.y * s) * hl;
    float Aw = (M2.x * c + M2.y * s) * hl;
    float Bx = (M0.y * c - M0.x * s) * hw;
    float By = (M1.y * c - M1.x * s) * hw;
    float Bw = (M2.y * c - M2.x * s) * hw;
    float Cx = M0.z * hh;
    float Cy = M1.z * hh;
    float Cw = M2.z * hh;

    float xp = bx + Ax, xm = bx - Ax;
    float X0 = xp + Bx, X1 = xp - Bx, X2 = xm + Bx, X3 = xm - Bx;
    float yp = by + Ay, ym = by - Ay;
    float Y0 = yp + By, Y1 = yp - By, Y2 = ym + By, Y3 = ym - By;
    float wp = bw + Aw, wm = bw - Aw;
    float W0 = wp + Bw, W1 = wp - Bw, W2 = wm + Bw, W3 = wm - Bw;

    float minx = 1e30f, maxx = -1e30f, miny = 1e30f, maxy = -1e30f;
    corner_minmax(X0 + Cx, Y0 + Cy, W0 + Cw, minx, maxx, miny, maxy);
    corner_minmax(X0 - Cx, Y0 - Cy, W0 - Cw, minx, maxx, miny, maxy);
    corner_minmax(X1 + Cx, Y1 + Cy, W1 + Cw, minx, maxx, miny, maxy);
    corner_minmax(X1 - Cx, Y1 - Cy, W1 - Cw, minx, maxx, miny, maxy);
    corner_minmax(X2 + Cx, Y2 + Cy, W2 + Cw, minx, maxx, miny, maxy);
    corner_minmax(X2 - Cx, Y2 - Cy, W2 - Cw, minx, maxx, miny, maxy);
    corner_minmax(X3 + Cx, Y3 + Cy, W3 + Cw, minx, maxx, miny, maxy);
    corner_minmax(X3 - Cx, Y3 - Cy, W3 - Cw, minx, maxx, miny, maxy);

    float2 hwd = ((const float2*)imgsh)[i];
    float H = hwd.x, W = hwd.y;
    float px1 = fminf(fmaxf(minx, 0.f), W);
    float px2 = fminf(fmaxf(maxx, 0.f), W);
    float py1 = fminf(fmaxf(miny, 0.f), H);
    float py2 = fminf(fmaxf(maxy, 0.f), H);

    float4 g = ((const float4*)gt2d)[i];

    float ix1 = fmaxf(px1, g.x);
    float iy1 = fmaxf(py1, g.y);
    float ix2 = fminf(px2, g.z);
    float iy2 = fminf(py2, g.w);
    float inter = fmaxf(ix2 - ix1, 0.f) * fmaxf(iy2 - iy1, 0.f);
    float pa = (px2 - px1) * (py2 - py1);
    float ga = (g.z - g.x) * (g.w - g.y);
    float uni = pa + ga - inter + EPS_A;
    float iou = inter / uni;

    float cx1 = fminf(px1, g.x);
    float cy1 = fminf(py1, g.y);
    float cx2 = fmaxf(px2, g.z);
    float cy2 = fmaxf(py2, g.w);
    float carea = fmaxf(cx2 - cx1, 0.f) * fmaxf(cy2 - cy1, 0.f) + EPS_A;
    float giou = iou - (carea - uni) / carea;
    return 1.0f - giou;   // >= 0
}

__global__ void __launch_bounds__(256) fused_kernel(
        const float* __restrict__ pred,      // N x 7
        const float* __restrict__ gt2d,      // N x 4
        const float* __restrict__ l2i,       // N x 16
        const float* __restrict__ imgsh,     // N x 2
        const int*   __restrict__ ids,       // N
        unsigned int* __restrict__ table,    // NUM_OBJECTS (+ acc after it)
        float* __restrict__ out,
        int n) {
    cg::grid_group grid = cg::this_grid();
    int t = blockIdx.x * blockDim.x + threadIdx.x;
    float* acc = (float*)(table + NUM_OBJECTS);  // 2 floats (within zeroed uint4)

    // ---- phase 1a: zero table + acc (one uint4 per thread) ----
    if (t <= TABLE_VEC4) {   // 20001 vec4 = table + acc/pad
        ((uint4*)table)[t] = make_uint4(0u, 0u, 0u, 0u);
    }

    // ---- phase 1b: compute 4 box losses into registers (table-independent,
    //      overlaps the zeroing + barrier) ----
    int i0 = t * 4;
    bool active = i0 < n;
    bool full = (i0 + 3) < n;
    unsigned int pk[4] = {0u, 0u, 0u, 0u};
    int idv[4] = {0, 0, 0, 0};
    if (active) {
        float p[28];
        const float4* pp = (const float4*)(pred + (size_t)i0 * 7);
        float4 P0 = pp[0], P1 = pp[1], P2 = pp[2], P3 = pp[3];
        float4 P4 = pp[4], P5 = pp[5], P6 = pp[6];
        p[0]=P0.x; p[1]=P0.y; p[2]=P0.z; p[3]=P0.w;
        p[4]=P1.x; p[5]=P1.y; p[6]=P1.z; p[7]=P1.w;
        p[8]=P2.x; p[9]=P2.y; p[10]=P2.z; p[11]=P2.w;
        p[12]=P3.x; p[13]=P3.y; p[14]=P3.z; p[15]=P3.w;
        p[16]=P4.x; p[17]=P4.y; p[18]=P4.z; p[19]=P4.w;
        p[20]=P5.x; p[21]=P5.y; p[22]=P5.z; p[23]=P5.w;
        p[24]=P6.x; p[25]=P6.y; p[26]=P6.z; p[27]=P6.w;

        int4 id4 = *(const int4*)(ids + i0);
        idv[0] = id4.x; idv[1] = id4.y; idv[2] = id4.z; idv[3] = id4.w;

#pragma unroll
        for (int j = 0; j < 4; ++j) {
            if (full || (i0 + j) < n) {
                float loss = box_loss(p, j, l2i, imgsh, gt2d, i0 + j);
                pk[j] = ((unsigned int)(loss * LOSS_SCALE_F + 0.5f) << 8) | 1u;
            }
        }
    }

    grid.sync();   // table globally zeroed; losses in registers

    // ---- phase 2: scatter atomics ----
    if (active) {
#pragma unroll
        for (int j = 0; j < 4; ++j) {
            if (pk[j]) atomicAdd(&table[idv[j]], pk[j]);
        }
    }

    grid.sync();   // all atomics done; fence makes them visible

    // ---- phase 3: segment reduce (one uint4 per thread covers 80000) ----
    float sm = 0.f, pr = 0.f;
    if (t < TABLE_VEC4) {
        uint4 w = ((const uint4*)table)[t];
        unsigned int c0 = w.x & 0xFFu, c1 = w.y & 0xFFu;
        unsigned int c2 = w.z & 0xFFu, c3 = w.w & 0xFFu;
        if (c0) { sm += (float)(w.x >> 8) * INV_LOSS_SCALE_F / (float)c0; pr += 1.f; }
        if (c1) { sm += (float)(w.y >> 8) * INV_LOSS_SCALE_F / (float)c1; pr += 1.f; }
        if (c2) { sm += (float)(w.z >> 8) * INV_LOSS_SCALE_F / (float)c2; pr += 1.f; }
        if (c3) { sm += (float)(w.w >> 8) * INV_LOSS_SCALE_F / (float)c3; pr += 1.f; }
    }
#pragma unroll
    for (int off = 32; off > 0; off >>= 1) {
        sm += __shfl_down(sm, off);
        pr += __shfl_down(pr, off);
    }
    __shared__ float ssm[4], spr[4];
    int lane = threadIdx.x & 63;
    int wid = threadIdx.x >> 6;
    if (lane == 0) { ssm[wid] = sm; spr[wid] = pr; }
    __syncthreads();
    if (threadIdx.x == 0) {
        float a = 0.f, b2 = 0.f;
#pragma unroll
        for (int k = 0; k < 4; ++k) { a += ssm[k]; b2 += spr[k]; }
        atomicAdd(&acc[0], a);
        atomicAdd(&acc[1], b2);
    }

    grid.sync();   // acc complete

    if (t == 0) {
        out[0] = acc[0] / acc[1];   // LOSS_WEIGHT == 1.0
    }
}

// ------------------- non-cooperative fallback path -------------------
__global__ void zero_ws(uint4* __restrict__ ws) {
    int i = blockIdx.x * blockDim.x + threadIdx.x;
    if (i < ZERO_VEC16) ws[i] = make_uint4(0u, 0u, 0u, 0u);
}

__global__ void __launch_bounds__(256) loss_only(
        const float* __restrict__ pred, const float* __restrict__ gt2d,
        const float* __restrict__ l2i, const float* __restrict__ imgsh,
        const int* __restrict__ ids, unsigned int* __restrict__ table, int n) {
    int t = blockIdx.x * blockDim.x + threadIdx.x;
    int i0 = t * 4;
    if (i0 >= n) return;
    bool full = (i0 + 3) < n;
    float p[28];
    const float4* pp = (const float4*)(pred + (size_t)i0 * 7);
    float4 P0 = pp[0], P1 = pp[1], P2 = pp[2], P3 = pp[3];
    float4 P4 = pp[4], P5 = pp[5], P6 = pp[6];
    p[0]=P0.x; p[1]=P0.y; p[2]=P0.z; p[3]=P0.w;
    p[4]=P1.x; p[5]=P1.y; p[6]=P1.z; p[7]=P1.w;
    p[8]=P2.x; p[9]=P2.y; p[10]=P2.z; p[11]=P2.w;
    p[12]=P3.x; p[13]=P3.y; p[14]=P3.z; p[15]=P3.w;
    p[16]=P4.x; p[17]=P4.y; p[18]=P4.z; p[19]=P4.w;
    p[20]=P5.x; p[21]=P5.y; p[22]=P5.z; p[23]=P5.w;
    p[24]=P6.x; p[25]=P6.y; p[26]=P6.z; p[27]=P6.w;
    int4 id4 = *(const int4*)(ids + i0);
    int idv[4] = {id4.x, id4.y, id4.z, id4.w};
#pragma unroll
    for (int j = 0; j < 4; ++j) {
        if (!full && (i0 + j) >= n) break;
        float loss = box_loss(p, j, l2i, imgsh, gt2d, i0 + j);
        unsigned int pk = ((unsigned int)(loss * LOSS_SCALE_F + 0.5f) << 8) | 1u;
        atomicAdd(&table[idv[j]], pk);
    }
}

__global__ void __launch_bounds__(256) seg_reduce(
        const uint4* __restrict__ table4, float* __restrict__ acc,
        unsigned int* __restrict__ ticket, float* __restrict__ out) {
    int i = blockIdx.x * blockDim.x + threadIdx.x;
    float sm = 0.f, pr = 0.f;
    if (i < TABLE_VEC4) {
        uint4 w = table4[i];
        unsigned int c0 = w.x & 0xFFu, c1 = w.y & 0xFFu;
        unsigned int c2 = w.z & 0xFFu, c3 = w.w & 0xFFu;
        if (c0) { sm += (float)(w.x >> 8) * INV_LOSS_SCALE_F / (float)c0; pr += 1.f; }
        if (c1) { sm += (float)(w.y >> 8) * INV_LOSS_SCALE_F / (float)c1; pr += 1.f; }
        if (c2) { sm += (float)(w.z >> 8) * INV_LOSS_SCALE_F / (float)c2; pr += 1.f; }
        if (c3) { sm += (float)(w.w >> 8) * INV_LOSS_SCALE_F / (float)c3; pr += 1.f; }
    }
#pragma unroll
    for (int off = 32; off > 0; off >>= 1) {
        sm += __shfl_down(sm, off);
        pr += __shfl_down(pr, off);
    }
    __shared__ float ssm[4], spr[4];
    int lane = threadIdx.x & 63;
    int wid = threadIdx.x >> 6;
    if (lane == 0) { ssm[wid] = sm; spr[wid] = pr; }
    __syncthreads();
    if (threadIdx.x == 0) {
        float a = 0.f, b2 = 0.f;
#pragma unroll
        for (int k = 0; k < 4; ++k) { a += ssm[k]; b2 += spr[k]; }
        atomicAdd(&acc[0], a);
        atomicAdd(&acc[1], b2);
        __threadfence();
        unsigned int old = atomicAdd(ticket, 1u);
        if (old == gridDim.x - 1) {
            float s = atomicAdd(&acc[0], 0.f);
            float pcnt = atomicAdd(&acc[1], 0.f);
            out[0] = s / pcnt;
        }
    }
}

extern "C" void kernel_launch(void* const* d_in, const int* in_sizes, int n_in,
                              void* d_out, int out_size, void* d_ws, size_t ws_size,
                              hipStream_t stream) {
    const float* pred  = (const float*)d_in[0];
    const float* gt2d  = (const float*)d_in[1];
    const float* l2i   = (const float*)d_in[2];
    const float* imgsh = (const float*)d_in[3];
    const int*   ids   = (const int*)d_in[4];
    float* out = (float*)d_out;

    int n = in_sizes[0] / 7;
    int block = 256;
    int nthreads = (n + 3) / 4;
    int grid1 = (nthreads + block - 1) / block;   // 391 blocks: co-resident
                                                  // (4 waves/blk, ~32 waves/CU cap)

    unsigned int* table  = (unsigned int*)d_ws;

    void* args[] = {(void*)&pred, (void*)&gt2d, (void*)&l2i, (void*)&imgsh,
                    (void*)&ids, (void*)&table, (void*)&out, (void*)&n};
    hipError_t err = hipLaunchCooperativeKernel((void*)fused_kernel,
                                                dim3(grid1), dim3(block),
                                                args, 0, stream);
    if (err != hipSuccess) {
        // fallback: 3-kernel chain (R6 structure)
        float*        acc    = (float*)(table + NUM_OBJECTS);
        unsigned int* ticket = (unsigned int*)(acc + 2);
        int gridz = (ZERO_VEC16 + block - 1) / block;
        zero_ws<<<gridz, block, 0, stream>>>((uint4*)d_ws);
        loss_only<<<grid1, block, 0, stream>>>(pred, gt2d, l2i, imgsh, ids, table, n);
        int grid2 = (TABLE_VEC4 + block - 1) / block;
        seg_reduce<<<grid2, block, 0, stream>>>((const uint4*)table, acc, ticket, out);
    }
}

// Round 8
// 35.077 us; speedup vs baseline: 4.9604x; 4.9604x over previous
//
#include <hip/hip_runtime.h>
#include <hip/hip_bf16.h>
#include <math.h>

#define NUM_OBJECTS 80000
#define EPS_W 1e-5f
#define EPS_A 1e-7f

// packed per-object accumulator (u32): bits [31:8] = sum(loss) in 2^18 fixed
// point, bits [7:0] = count. loss in [0,2]; per-object count ~Poisson(5),
// max ~30 << 255; sum < 2^24 -> no overflow, count never carries into sum.
#define LOSS_SCALE_F 262144.0f   // 2^18
#define INV_LOSS_SCALE_F (1.0f / 262144.0f)

// ws layout: table 80000 u32 (=20000 uint4) | acc 2 f32 + ticket + pad (1 uint4)
#define TABLE_VEC4 20000
#define ZERO_VEC16 20001

// float4 with only 4-byte alignment guarantee: compiles to global_load_dwordx4
// without assuming 16B alignment (pred rows are 28B apart).
typedef float f32x4u __attribute__((ext_vector_type(4), aligned(4)));

__global__ void zero_ws(uint4* __restrict__ ws) {
    int i = blockIdx.x * blockDim.x + threadIdx.x;
    if (i < ZERO_VEC16) ws[i] = make_uint4(0u, 0u, 0u, 0u);
}

__device__ __forceinline__ void corner_minmax(float X, float Y, float Wc,
                                              float& minx, float& maxx,
                                              float& miny, float& maxy) {
    float wd = fmaxf(Wc, EPS_W);
    float r  = __builtin_amdgcn_rcpf(wd);   // v_rcp_f32, ~1 ulp
    float xi = X * r;
    float yi = Y * r;
    minx = fminf(minx, xi); maxx = fmaxf(maxx, xi);
    miny = fminf(miny, yi); maxy = fmaxf(maxy, yi);
}

__global__ void __launch_bounds__(256) loss_kernel(
        const float* __restrict__ pred,      // N x 7
        const float* __restrict__ gt2d,      // N x 4
        const float* __restrict__ l2i,       // N x 16
        const float* __restrict__ imgsh,     // N x 2
        const int*   __restrict__ ids,       // N
        unsigned int* __restrict__ table,    // NUM_OBJECTS
        int n) {
    int i = blockIdx.x * blockDim.x + threadIdx.x;
    if (i >= n) return;

    // 8 independent loads, all issued before any use
    f32x4u pa = *(const f32x4u*)(pred + 7 * (size_t)i);      // x y z l
    f32x4u pb = *(const f32x4u*)(pred + 7 * (size_t)i + 3);  // l w h yaw
    const float4* M = (const float4*)(l2i + 16 * (size_t)i);
    float4 M0 = M[0];
    float4 M1 = M[1];
    float4 M2 = M[2];
    float4 g   = ((const float4*)gt2d)[i];
    float2 hwd = ((const float2*)imgsh)[i];
    int oid    = ids[i];

    float x = pa.x, y = pa.y, z = pa.z;
    float hl = 0.5f * pa.w, hw = 0.5f * pb.y, hh = 0.5f * pb.z;
    float yaw = pb.w;
    float s, c;
    __sincosf(yaw, &s, &c);

    // row·corner = b + sx*A + sy*B + sz*C  (affine in the sign triple)
    float bx = M0.x * x + M0.y * y + M0.z * z + M0.w;
    float by = M1.x * x + M1.y * y + M1.z * z + M1.w;
    float bw = M2.x * x + M2.y * y + M2.z * z + M2.w;
    float Ax = (M0.x * c + M0.y * s) * hl;
    float Ay = (M1.x * c + M1.y * s) * hl;
    float Aw = (M2.x * c + M2.y * s) * hl;
    float Bx = (M0.y * c - M0.x * s) * hw;
    float By = (M1.y * c - M1.x * s) * hw;
    float Bw = (M2.y * c - M2.x * s) * hw;
    float Cx = M0.z * hh;
    float Cy = M1.z * hh;
    float Cw = M2.z * hh;

    float xp = bx + Ax, xm = bx - Ax;
    float X0 = xp + Bx, X1 = xp - Bx, X2 = xm + Bx, X3 = xm - Bx;
    float yp = by + Ay, ym = by - Ay;
    float Y0 = yp + By, Y1 = yp - By, Y2 = ym + By, Y3 = ym - By;
    float wp = bw + Aw, wm = bw - Aw;
    float W0 = wp + Bw, W1 = wp - Bw, W2 = wm + Bw, W3 = wm - Bw;

    float minx = 1e30f, maxx = -1e30f, miny = 1e30f, maxy = -1e30f;
    corner_minmax(X0 + Cx, Y0 + Cy, W0 + Cw, minx, maxx, miny, maxy);
    corner_minmax(X0 - Cx, Y0 - Cy, W0 - Cw, minx, maxx, miny, maxy);
    corner_minmax(X1 + Cx, Y1 + Cy, W1 + Cw, minx, maxx, miny, maxy);
    corner_minmax(X1 - Cx, Y1 - Cy, W1 - Cw, minx, maxx, miny, maxy);
    corner_minmax(X2 + Cx, Y2 + Cy, W2 + Cw, minx, maxx, miny, maxy);
    corner_minmax(X2 - Cx, Y2 - Cy, W2 - Cw, minx, maxx, miny, maxy);
    corner_minmax(X3 + Cx, Y3 + Cy, W3 + Cw, minx, maxx, miny, maxy);
    corner_minmax(X3 - Cx, Y3 - Cy, W3 - Cw, minx, maxx, miny, maxy);

    float H = hwd.x, W = hwd.y;
    float px1 = fminf(fmaxf(minx, 0.f), W);
    float px2 = fminf(fmaxf(maxx, 0.f), W);
    float py1 = fminf(fmaxf(miny, 0.f), H);
    float py2 = fminf(fmaxf(maxy, 0.f), H);

    float ix1 = fmaxf(px1, g.x);
    float iy1 = fmaxf(py1, g.y);
    float ix2 = fminf(px2, g.z);
    float iy2 = fminf(py2, g.w);
    float inter = fmaxf(ix2 - ix1, 0.f) * fmaxf(iy2 - iy1, 0.f);
    float pa2 = (px2 - px1) * (py2 - py1);
    float ga = (g.z - g.x) * (g.w - g.y);
    float uni = pa2 + ga - inter + EPS_A;
    float iou = inter / uni;

    float cx1 = fminf(px1, g.x);
    float cy1 = fminf(py1, g.y);
    float cx2 = fmaxf(px2, g.z);
    float cy2 = fmaxf(py2, g.w);
    float carea = fmaxf(cx2 - cx1, 0.f) * fmaxf(cy2 - cy1, 0.f) + EPS_A;
    float giou = iou - (carea - uni) / carea;
    float loss = 1.0f - giou;   // >= 0

    unsigned int pk = ((unsigned int)(loss * LOSS_SCALE_F + 0.5f) << 8) | 1u;
    atomicAdd(&table[oid], pk);
}

__global__ void __launch_bounds__(256) seg_reduce(
        const uint4* __restrict__ table4,    // NUM_OBJECTS/4 entries
        float* __restrict__ acc,             // acc[0]=sum of means, acc[1]=n present
        unsigned int* __restrict__ ticket,
        float* __restrict__ out) {
    int i = blockIdx.x * blockDim.x + threadIdx.x;
    float sm = 0.f, pr = 0.f;
    if (i < TABLE_VEC4) {
        uint4 w = table4[i];
        unsigned int c0 = w.x & 0xFFu, c1 = w.y & 0xFFu;
        unsigned int c2 = w.z & 0xFFu, c3 = w.w & 0xFFu;
        if (c0) { sm += (float)(w.x >> 8) * INV_LOSS_SCALE_F / (float)c0; pr += 1.f; }
        if (c1) { sm += (float)(w.y >> 8) * INV_LOSS_SCALE_F / (float)c1; pr += 1.f; }
        if (c2) { sm += (float)(w.z >> 8) * INV_LOSS_SCALE_F / (float)c2; pr += 1.f; }
        if (c3) { sm += (float)(w.w >> 8) * INV_LOSS_SCALE_F / (float)c3; pr += 1.f; }
    }
#pragma unroll
    for (int off = 32; off > 0; off >>= 1) {
        sm += __shfl_down(sm, off);
        pr += __shfl_down(pr, off);
    }
    __shared__ float ssm[4], spr[4];
    int lane = threadIdx.x & 63;
    int wid = threadIdx.x >> 6;
    if (lane == 0) { ssm[wid] = sm; spr[wid] = pr; }
    __syncthreads();
    if (threadIdx.x == 0) {
        float a = 0.f, b2 = 0.f;
#pragma unroll
        for (int k = 0; k < 4; ++k) { a += ssm[k]; b2 += spr[k]; }
        atomicAdd(&acc[0], a);
        atomicAdd(&acc[1], b2);
        __threadfence();
        unsigned int old = atomicAdd(ticket, 1u);
        if (old == gridDim.x - 1) {
            // atomic reads hit the coherence point (cross-XCD safe)
            float s = atomicAdd(&acc[0], 0.f);
            float pcnt = atomicAdd(&acc[1], 0.f);
            out[0] = s / pcnt;   // LOSS_WEIGHT == 1.0
        }
    }
}

extern "C" void kernel_launch(void* const* d_in, const int* in_sizes, int n_in,
                              void* d_out, int out_size, void* d_ws, size_t ws_size,
                              hipStream_t stream) {
    const float* pred  = (const float*)d_in[0];
    const float* gt2d  = (const float*)d_in[1];
    const float* l2i   = (const float*)d_in[2];
    const float* imgsh = (const float*)d_in[3];
    const int*   ids   = (const int*)d_in[4];
    float* out = (float*)d_out;

    int n = in_sizes[0] / 7;
    int block = 256;

    unsigned int* table  = (unsigned int*)d_ws;
    float*        acc    = (float*)(table + NUM_OBJECTS);  // 2 floats
    unsigned int* ticket = (unsigned int*)(acc + 2);       // 1 u32

    int gridz = (ZERO_VEC16 + block - 1) / block;          // 79
    zero_ws<<<gridz, block, 0, stream>>>((uint4*)d_ws);

    int grid1 = (n + block - 1) / block;                   // 1563: ~6 waves/SIMD
    loss_kernel<<<grid1, block, 0, stream>>>(pred, gt2d, l2i, imgsh, ids, table, n);

    int grid2 = (TABLE_VEC4 + block - 1) / block;          // 79
    seg_reduce<<<grid2, block, 0, stream>>>((const uint4*)table, acc, ticket, out);
}